// Round 1
// baseline (2746.295 us; speedup 1.0000x reference)
//
#include <hip/hip_runtime.h>

#define HID 52
#define HID2 104

// z[i] = (1 + eps) * h[i], vectorized float4 (n4 = N*HID/4)
__global__ void init_z_kernel(const float* __restrict__ h, const float* __restrict__ eps,
                              float* __restrict__ z, int n4) {
    int t = blockIdx.x * blockDim.x + threadIdx.x;
    if (t < n4) {
        float s = 1.0f + eps[0];
        float4 v = ((const float4*)h)[t];
        v.x *= s; v.y *= s; v.z *= s; v.w *= s;
        ((float4*)z)[t] = v;
    }
}

// one thread per (edge, feature): z[dst[e]*HID + f] += h[src[e]*HID + f]
// total = E*HID (fits in 32-bit: 166.4M)
__global__ void scatter_kernel(const float* __restrict__ h, const int* __restrict__ src,
                               const int* __restrict__ dst, float* __restrict__ z,
                               unsigned int total) {
    unsigned int t = blockIdx.x * blockDim.x + threadIdx.x;
    if (t >= total) return;
    unsigned int e = t / HID;          // magic-mul, cheap
    unsigned int f = t - e * HID;
    int s = src[e];
    int d = dst[e];
    float v = h[(size_t)s * HID + f];
    unsafeAtomicAdd(&z[(size_t)d * HID + f], v);   // hw global_atomic_add_f32
}

// thread-per-node 2-layer MLP: hout = relu( relu(z@w1 + b1) @ w2 + b2 )
// weights staged in LDS, all LDS reads as float4 (b128)
__global__ void mlp_kernel(const float* __restrict__ z,
                           const float* __restrict__ w1, const float* __restrict__ b1,
                           const float* __restrict__ w2, const float* __restrict__ b2,
                           float* __restrict__ hout, int n) {
    __shared__ float s_w1[HID * HID2];   // [52][104] row-major
    __shared__ float s_w2[HID2 * HID];   // [104][52] row-major
    __shared__ float s_b1[HID2];
    __shared__ float s_b2[HID];
    int tid = threadIdx.x;
    for (int i = tid; i < HID * HID2; i += blockDim.x) s_w1[i] = w1[i];
    for (int i = tid; i < HID2 * HID; i += blockDim.x) s_w2[i] = w2[i];
    if (tid < HID2) s_b1[tid] = b1[tid];
    if (tid < HID)  s_b2[tid] = b2[tid];
    __syncthreads();

    int node = blockIdx.x * blockDim.x + tid;
    if (node >= n) return;

    float x[HID];
    const float4* zr = (const float4*)(z + (size_t)node * HID);
#pragma unroll
    for (int i = 0; i < HID / 4; i++) {
        float4 v = zr[i];
        x[4*i+0] = v.x; x[4*i+1] = v.y; x[4*i+2] = v.z; x[4*i+3] = v.w;
    }

    float4 acc[HID / 4];
#pragma unroll
    for (int k = 0; k < HID / 4; k++) acc[k] = ((const float4*)s_b2)[k];

    for (int j0 = 0; j0 < HID2; j0 += 4) {
        float4 s = *(const float4*)&s_b1[j0];
#pragma unroll
        for (int i = 0; i < HID; i++) {
            float4 w = *(const float4*)&s_w1[i * HID2 + j0];
            s.x = fmaf(x[i], w.x, s.x);
            s.y = fmaf(x[i], w.y, s.y);
            s.z = fmaf(x[i], w.z, s.z);
            s.w = fmaf(x[i], w.w, s.w);
        }
        s.x = fmaxf(s.x, 0.f); s.y = fmaxf(s.y, 0.f);
        s.z = fmaxf(s.z, 0.f); s.w = fmaxf(s.w, 0.f);
        const float4* r0 = (const float4*)&s_w2[(j0+0) * HID];
        const float4* r1 = (const float4*)&s_w2[(j0+1) * HID];
        const float4* r2 = (const float4*)&s_w2[(j0+2) * HID];
        const float4* r3 = (const float4*)&s_w2[(j0+3) * HID];
#pragma unroll
        for (int k = 0; k < HID / 4; k++) {
            float4 a = acc[k];
            float4 w0 = r0[k], w1v = r1[k], w2v = r2[k], w3v = r3[k];
            a.x = fmaf(s.x, w0.x, a.x); a.x = fmaf(s.y, w1v.x, a.x);
            a.x = fmaf(s.z, w2v.x, a.x); a.x = fmaf(s.w, w3v.x, a.x);
            a.y = fmaf(s.x, w0.y, a.y); a.y = fmaf(s.y, w1v.y, a.y);
            a.y = fmaf(s.z, w2v.y, a.y); a.y = fmaf(s.w, w3v.y, a.y);
            a.z = fmaf(s.x, w0.z, a.z); a.z = fmaf(s.y, w1v.z, a.z);
            a.z = fmaf(s.z, w2v.z, a.z); a.z = fmaf(s.w, w3v.z, a.z);
            a.w = fmaf(s.x, w0.w, a.w); a.w = fmaf(s.y, w1v.w, a.w);
            a.w = fmaf(s.z, w2v.w, a.w); a.w = fmaf(s.w, w3v.w, a.w);
            acc[k] = a;
        }
    }

    float4* orow = (float4*)(hout + (size_t)node * HID);
#pragma unroll
    for (int k = 0; k < HID / 4; k++) {
        float4 a = acc[k];
        a.x = fmaxf(a.x, 0.f); a.y = fmaxf(a.y, 0.f);
        a.z = fmaxf(a.z, 0.f); a.w = fmaxf(a.w, 0.f);
        orow[k] = a;
    }
}

// out = concat(x,h1,h2,h3) @ lin_w + lin_b ; lin_w [208][52] in LDS
__global__ void final_kernel(const float* __restrict__ h0, const float* __restrict__ h1,
                             const float* __restrict__ h2, const float* __restrict__ h3,
                             const float* __restrict__ lin_w, const float* __restrict__ lin_b,
                             float* __restrict__ out, int n) {
    __shared__ float s_lw[4 * HID * HID];   // [208][52]
    __shared__ float s_lb[HID];
    int tid = threadIdx.x;
    for (int i = tid; i < 4 * HID * HID; i += blockDim.x) s_lw[i] = lin_w[i];
    if (tid < HID) s_lb[tid] = lin_b[tid];
    __syncthreads();

    int node = blockIdx.x * blockDim.x + tid;
    if (node >= n) return;

    float4 acc[HID / 4];
#pragma unroll
    for (int k = 0; k < HID / 4; k++) acc[k] = ((const float4*)s_lb)[k];

    const float* srcs[4] = {h0, h1, h2, h3};
#pragma unroll
    for (int b = 0; b < 4; b++) {
        const float4* xr = (const float4*)(srcs[b] + (size_t)node * HID);
#pragma unroll
        for (int i4 = 0; i4 < HID / 4; i4++) {
            float4 v = xr[i4];
            int ib = b * HID + 4 * i4;
            const float4* w0 = (const float4*)&s_lw[(ib+0) * HID];
            const float4* w1v = (const float4*)&s_lw[(ib+1) * HID];
            const float4* w2v = (const float4*)&s_lw[(ib+2) * HID];
            const float4* w3v = (const float4*)&s_lw[(ib+3) * HID];
#pragma unroll
            for (int k = 0; k < HID / 4; k++) {
                float4 a = acc[k];
                float4 a0 = w0[k], a1 = w1v[k], a2 = w2v[k], a3 = w3v[k];
                a.x = fmaf(v.x, a0.x, a.x); a.x = fmaf(v.y, a1.x, a.x);
                a.x = fmaf(v.z, a2.x, a.x); a.x = fmaf(v.w, a3.x, a.x);
                a.y = fmaf(v.x, a0.y, a.y); a.y = fmaf(v.y, a1.y, a.y);
                a.y = fmaf(v.z, a2.y, a.y); a.y = fmaf(v.w, a3.y, a.y);
                a.z = fmaf(v.x, a0.z, a.z); a.z = fmaf(v.y, a1.z, a.z);
                a.z = fmaf(v.z, a2.z, a.z); a.z = fmaf(v.w, a3.z, a.z);
                a.w = fmaf(v.x, a0.w, a.w); a.w = fmaf(v.y, a1.w, a.w);
                a.w = fmaf(v.z, a2.w, a.w); a.w = fmaf(v.w, a3.w, a.w);
                acc[k] = a;
            }
        }
    }

    float4* orow = (float4*)(out + (size_t)node * HID);
#pragma unroll
    for (int k = 0; k < HID / 4; k++) orow[k] = acc[k];
}

extern "C" void kernel_launch(void* const* d_in, const int* in_sizes, int n_in,
                              void* d_out, int out_size, void* d_ws, size_t ws_size,
                              hipStream_t stream) {
    const float* x     = (const float*)d_in[0];
    const int*   ei    = (const int*)d_in[1];
    const float* w1    = (const float*)d_in[2];
    const float* b1    = (const float*)d_in[3];
    const float* w2    = (const float*)d_in[4];
    const float* b2    = (const float*)d_in[5];
    const float* eps   = (const float*)d_in[6];
    const float* lin_w = (const float*)d_in[7];
    const float* lin_b = (const float*)d_in[8];
    float* out = (float*)d_out;

    const int N = in_sizes[0] / HID;       // 100000
    const int E = in_sizes[1] / 2;         // 3200000
    const int* src = ei;
    const int* dst = ei + E;

    float* ws = (float*)d_ws;
    float* z  = ws;
    float* h1 = ws + (size_t)N * HID;
    float* h2 = h1 + (size_t)N * HID;
    float* h3 = h2 + (size_t)N * HID;
    float* houts[3] = {h1, h2, h3};

    const int n4 = N * HID / 4;
    const unsigned int etotal = (unsigned int)E * HID;
    const int BLK = 256;
    dim3 blk(BLK);
    dim3 grid_init((n4 + BLK - 1) / BLK);
    dim3 grid_scat((etotal + BLK - 1) / BLK);
    dim3 grid_node((N + BLK - 1) / BLK);

    const float* hprev = x;
    for (int l = 0; l < 3; l++) {
        init_z_kernel<<<grid_init, blk, 0, stream>>>(hprev, eps + l, z, n4);
        scatter_kernel<<<grid_scat, blk, 0, stream>>>(hprev, src, dst, z, etotal);
        mlp_kernel<<<grid_node, blk, 0, stream>>>(z,
                                                  w1 + (size_t)l * HID * HID2,
                                                  b1 + (size_t)l * HID2,
                                                  w2 + (size_t)l * HID2 * HID,
                                                  b2 + (size_t)l * HID,
                                                  houts[l], N);
        hprev = houts[l];
    }
    final_kernel<<<grid_node, blk, 0, stream>>>(x, h1, h2, h3, lin_w, lin_b, out, N);
}

// Round 2
// 1253.575 us; speedup vs baseline: 2.1908x; 2.1908x over previous
//
#include <hip/hip_runtime.h>

#define HID 52
#define HID2 104
#define SCAN_CHUNK 1024   // 256 threads x 4 elems

// ---------- CSR build ----------

__global__ void hist_kernel(const int* __restrict__ dst, int* __restrict__ deg, int E) {
    int e = blockIdx.x * blockDim.x + threadIdx.x;
    if (e < E) atomicAdd(&deg[dst[e]], 1);
}

__global__ void chunk_sum_kernel(const int* __restrict__ deg, int* __restrict__ bsum, int n) {
    __shared__ int sd[256];
    int base = blockIdx.x * SCAN_CHUNK;
    int s = 0;
    for (int i = threadIdx.x; i < SCAN_CHUNK; i += 256) {
        int g = base + i;
        s += (g < n) ? deg[g] : 0;
    }
    sd[threadIdx.x] = s;
    __syncthreads();
    for (int off = 128; off > 0; off >>= 1) {
        if (threadIdx.x < off) sd[threadIdx.x] += sd[threadIdx.x + off];
        __syncthreads();
    }
    if (threadIdx.x == 0) bsum[blockIdx.x] = sd[0];
}

// single block, 128 threads; nb <= 128. exclusive scan of bsum in place.
__global__ void scan_bsum_kernel(int* __restrict__ bsum, int nb,
                                 int* __restrict__ rowstart, int N, int E) {
    __shared__ int sd[128];
    int tid = threadIdx.x;
    int v = (tid < nb) ? bsum[tid] : 0;
    sd[tid] = v;
    __syncthreads();
    for (int off = 1; off < 128; off <<= 1) {
        int t = (tid >= off) ? sd[tid - off] : 0;
        __syncthreads();
        sd[tid] += t;
        __syncthreads();
    }
    if (tid < nb) bsum[tid] = sd[tid] - v;   // exclusive
    if (tid == 0) rowstart[N] = E;
}

__global__ void chunk_scan_kernel(const int* __restrict__ deg, const int* __restrict__ bsum_ex,
                                  int* __restrict__ rowstart, int* __restrict__ cursor, int n) {
    __shared__ int sd[256];
    int tid = threadIdx.x;
    int base = blockIdx.x * SCAN_CHUNK + tid * 4;
    int v0 = (base + 0 < n) ? deg[base + 0] : 0;
    int v1 = (base + 1 < n) ? deg[base + 1] : 0;
    int v2 = (base + 2 < n) ? deg[base + 2] : 0;
    int v3 = (base + 3 < n) ? deg[base + 3] : 0;
    int tsum = v0 + v1 + v2 + v3;
    sd[tid] = tsum;
    __syncthreads();
    for (int off = 1; off < 256; off <<= 1) {
        int t = (tid >= off) ? sd[tid - off] : 0;
        __syncthreads();
        sd[tid] += t;
        __syncthreads();
    }
    int ex = sd[tid] - tsum + bsum_ex[blockIdx.x];
    int p0 = ex, p1 = p0 + v0, p2 = p1 + v1, p3 = p2 + v2;
    if (base + 0 < n) { rowstart[base + 0] = p0; cursor[base + 0] = p0; }
    if (base + 1 < n) { rowstart[base + 1] = p1; cursor[base + 1] = p1; }
    if (base + 2 < n) { rowstart[base + 2] = p2; cursor[base + 2] = p2; }
    if (base + 3 < n) { rowstart[base + 3] = p3; cursor[base + 3] = p3; }
}

__global__ void permute_kernel(const int* __restrict__ src, const int* __restrict__ dst,
                               int* __restrict__ cursor, int* __restrict__ srcsorted, int E) {
    int e = blockIdx.x * blockDim.x + threadIdx.x;
    if (e < E) {
        int d = dst[e];
        int pos = atomicAdd(&cursor[d], 1);
        srcsorted[pos] = src[e];
    }
}

// ---------- aggregation: one wave per node, lane f owns feature f ----------
// z[v] = (1+eps)*h[v] + sum_{e: dst=v} h[src[e]]
__global__ void agg_kernel(const float* __restrict__ h, const int* __restrict__ rowstart,
                           const int* __restrict__ srcsorted, const float* __restrict__ eps,
                           float* __restrict__ z, int n) {
    int wave = (blockIdx.x * blockDim.x + threadIdx.x) >> 6;
    int lane = threadIdx.x & 63;
    if (wave >= n) return;
    int beg = rowstart[wave];
    int end = rowstart[wave + 1];
    float acc0 = 0.f, acc1 = 0.f, acc2 = 0.f, acc3 = 0.f;
    for (int b = beg; b < end; b += 64) {
        int cnt = min(64, end - b);
        int idx = (lane < cnt) ? srcsorted[b + lane] : 0;
        int j = 0;
        for (; j + 4 <= cnt; j += 4) {
            int s0 = __shfl(idx, j + 0);
            int s1 = __shfl(idx, j + 1);
            int s2 = __shfl(idx, j + 2);
            int s3 = __shfl(idx, j + 3);
            if (lane < HID) {
                acc0 += h[(size_t)s0 * HID + lane];
                acc1 += h[(size_t)s1 * HID + lane];
                acc2 += h[(size_t)s2 * HID + lane];
                acc3 += h[(size_t)s3 * HID + lane];
            }
        }
        for (; j < cnt; j++) {
            int s = __shfl(idx, j);
            if (lane < HID) acc0 += h[(size_t)s * HID + lane];
        }
    }
    if (lane < HID) {
        float scale = 1.0f + eps[0];
        float self = h[(size_t)wave * HID + lane];
        z[(size_t)wave * HID + lane] = fmaf(scale, self, (acc0 + acc1) + (acc2 + acc3));
    }
}

// ---------- per-node 2-layer MLP (unchanged from R1) ----------
__global__ void mlp_kernel(const float* __restrict__ z,
                           const float* __restrict__ w1, const float* __restrict__ b1,
                           const float* __restrict__ w2, const float* __restrict__ b2,
                           float* __restrict__ hout, int n) {
    __shared__ float s_w1[HID * HID2];
    __shared__ float s_w2[HID2 * HID];
    __shared__ float s_b1[HID2];
    __shared__ float s_b2[HID];
    int tid = threadIdx.x;
    for (int i = tid; i < HID * HID2; i += blockDim.x) s_w1[i] = w1[i];
    for (int i = tid; i < HID2 * HID; i += blockDim.x) s_w2[i] = w2[i];
    if (tid < HID2) s_b1[tid] = b1[tid];
    if (tid < HID)  s_b2[tid] = b2[tid];
    __syncthreads();

    int node = blockIdx.x * blockDim.x + tid;
    if (node >= n) return;

    float x[HID];
    const float4* zr = (const float4*)(z + (size_t)node * HID);
#pragma unroll
    for (int i = 0; i < HID / 4; i++) {
        float4 v = zr[i];
        x[4*i+0] = v.x; x[4*i+1] = v.y; x[4*i+2] = v.z; x[4*i+3] = v.w;
    }

    float4 acc[HID / 4];
#pragma unroll
    for (int k = 0; k < HID / 4; k++) acc[k] = ((const float4*)s_b2)[k];

    for (int j0 = 0; j0 < HID2; j0 += 4) {
        float4 s = *(const float4*)&s_b1[j0];
#pragma unroll
        for (int i = 0; i < HID; i++) {
            float4 w = *(const float4*)&s_w1[i * HID2 + j0];
            s.x = fmaf(x[i], w.x, s.x);
            s.y = fmaf(x[i], w.y, s.y);
            s.z = fmaf(x[i], w.z, s.z);
            s.w = fmaf(x[i], w.w, s.w);
        }
        s.x = fmaxf(s.x, 0.f); s.y = fmaxf(s.y, 0.f);
        s.z = fmaxf(s.z, 0.f); s.w = fmaxf(s.w, 0.f);
        const float4* r0 = (const float4*)&s_w2[(j0+0) * HID];
        const float4* r1 = (const float4*)&s_w2[(j0+1) * HID];
        const float4* r2 = (const float4*)&s_w2[(j0+2) * HID];
        const float4* r3 = (const float4*)&s_w2[(j0+3) * HID];
#pragma unroll
        for (int k = 0; k < HID / 4; k++) {
            float4 a = acc[k];
            float4 w0 = r0[k], w1v = r1[k], w2v = r2[k], w3v = r3[k];
            a.x = fmaf(s.x, w0.x, a.x); a.x = fmaf(s.y, w1v.x, a.x);
            a.x = fmaf(s.z, w2v.x, a.x); a.x = fmaf(s.w, w3v.x, a.x);
            a.y = fmaf(s.x, w0.y, a.y); a.y = fmaf(s.y, w1v.y, a.y);
            a.y = fmaf(s.z, w2v.y, a.y); a.y = fmaf(s.w, w3v.y, a.y);
            a.z = fmaf(s.x, w0.z, a.z); a.z = fmaf(s.y, w1v.z, a.z);
            a.z = fmaf(s.z, w2v.z, a.z); a.z = fmaf(s.w, w3v.z, a.z);
            a.w = fmaf(s.x, w0.w, a.w); a.w = fmaf(s.y, w1v.w, a.w);
            a.w = fmaf(s.z, w2v.w, a.w); a.w = fmaf(s.w, w3v.w, a.w);
            acc[k] = a;
        }
    }

    float4* orow = (float4*)(hout + (size_t)node * HID);
#pragma unroll
    for (int k = 0; k < HID / 4; k++) {
        float4 a = acc[k];
        a.x = fmaxf(a.x, 0.f); a.y = fmaxf(a.y, 0.f);
        a.z = fmaxf(a.z, 0.f); a.w = fmaxf(a.w, 0.f);
        orow[k] = a;
    }
}

// ---------- final linear (unchanged from R1) ----------
__global__ void final_kernel(const float* __restrict__ h0, const float* __restrict__ h1,
                             const float* __restrict__ h2, const float* __restrict__ h3,
                             const float* __restrict__ lin_w, const float* __restrict__ lin_b,
                             float* __restrict__ out, int n) {
    __shared__ float s_lw[4 * HID * HID];
    __shared__ float s_lb[HID];
    int tid = threadIdx.x;
    for (int i = tid; i < 4 * HID * HID; i += blockDim.x) s_lw[i] = lin_w[i];
    if (tid < HID) s_lb[tid] = lin_b[tid];
    __syncthreads();

    int node = blockIdx.x * blockDim.x + tid;
    if (node >= n) return;

    float4 acc[HID / 4];
#pragma unroll
    for (int k = 0; k < HID / 4; k++) acc[k] = ((const float4*)s_lb)[k];

    const float* srcs[4] = {h0, h1, h2, h3};
#pragma unroll
    for (int b = 0; b < 4; b++) {
        const float4* xr = (const float4*)(srcs[b] + (size_t)node * HID);
#pragma unroll
        for (int i4 = 0; i4 < HID / 4; i4++) {
            float4 v = xr[i4];
            int ib = b * HID + 4 * i4;
            const float4* w0 = (const float4*)&s_lw[(ib+0) * HID];
            const float4* w1v = (const float4*)&s_lw[(ib+1) * HID];
            const float4* w2v = (const float4*)&s_lw[(ib+2) * HID];
            const float4* w3v = (const float4*)&s_lw[(ib+3) * HID];
#pragma unroll
            for (int k = 0; k < HID / 4; k++) {
                float4 a = acc[k];
                float4 a0 = w0[k], a1 = w1v[k], a2 = w2v[k], a3 = w3v[k];
                a.x = fmaf(v.x, a0.x, a.x); a.x = fmaf(v.y, a1.x, a.x);
                a.x = fmaf(v.z, a2.x, a.x); a.x = fmaf(v.w, a3.x, a.x);
                a.y = fmaf(v.x, a0.y, a.y); a.y = fmaf(v.y, a1.y, a.y);
                a.y = fmaf(v.z, a2.y, a.y); a.y = fmaf(v.w, a3.y, a.y);
                a.z = fmaf(v.x, a0.z, a.z); a.z = fmaf(v.y, a1.z, a.z);
                a.z = fmaf(v.z, a2.z, a.z); a.z = fmaf(v.w, a3.z, a.z);
                a.w = fmaf(v.x, a0.w, a.w); a.w = fmaf(v.y, a1.w, a.w);
                a.w = fmaf(v.z, a2.w, a.w); a.w = fmaf(v.w, a3.w, a.w);
                acc[k] = a;
            }
        }
    }

    float4* orow = (float4*)(out + (size_t)node * HID);
#pragma unroll
    for (int k = 0; k < HID / 4; k++) orow[k] = acc[k];
}

extern "C" void kernel_launch(void* const* d_in, const int* in_sizes, int n_in,
                              void* d_out, int out_size, void* d_ws, size_t ws_size,
                              hipStream_t stream) {
    const float* x     = (const float*)d_in[0];
    const int*   ei    = (const int*)d_in[1];
    const float* w1    = (const float*)d_in[2];
    const float* b1    = (const float*)d_in[3];
    const float* w2    = (const float*)d_in[4];
    const float* b2    = (const float*)d_in[5];
    const float* eps   = (const float*)d_in[6];
    const float* lin_w = (const float*)d_in[7];
    const float* lin_b = (const float*)d_in[8];
    float* out = (float*)d_out;

    const int N = in_sizes[0] / HID;       // 100000
    const int E = in_sizes[1] / 2;         // 3200000
    const int* src = ei;
    const int* dst = ei + E;

    // workspace layout
    float* ws = (float*)d_ws;
    float* z  = ws;
    float* h1 = ws + (size_t)N * HID;
    float* h2 = h1 + (size_t)N * HID;
    float* h3 = h2 + (size_t)N * HID;
    float* houts[3] = {h1, h2, h3};
    int* ibase     = (int*)(h3 + (size_t)N * HID);
    int* deg       = ibase;                 // N
    int* rowstart  = deg + N;               // N+1
    int* cursor    = rowstart + N + 1;      // N
    int* bsum      = cursor + N;            // <=128
    int* srcsorted = bsum + 128;            // E

    const int BLK = 256;
    const int NB = (N + SCAN_CHUNK - 1) / SCAN_CHUNK;   // 98
    dim3 blk(BLK);
    dim3 grid_edge((E + BLK - 1) / BLK);
    dim3 grid_node((N + BLK - 1) / BLK);
    dim3 grid_agg(((size_t)N * 64 + BLK - 1) / BLK);
    dim3 grid_chunk(NB);

    // ---- CSR build (once per call) ----
    hipMemsetAsync(deg, 0, (size_t)N * sizeof(int), stream);
    hist_kernel<<<grid_edge, blk, 0, stream>>>(dst, deg, E);
    chunk_sum_kernel<<<grid_chunk, blk, 0, stream>>>(deg, bsum, N);
    scan_bsum_kernel<<<1, 128, 0, stream>>>(bsum, NB, rowstart, N, E);
    chunk_scan_kernel<<<grid_chunk, blk, 0, stream>>>(deg, bsum, rowstart, cursor, N);
    permute_kernel<<<grid_edge, blk, 0, stream>>>(src, dst, cursor, srcsorted, E);

    // ---- layers ----
    const float* hprev = x;
    for (int l = 0; l < 3; l++) {
        agg_kernel<<<grid_agg, blk, 0, stream>>>(hprev, rowstart, srcsorted, eps + l, z, N);
        mlp_kernel<<<grid_node, blk, 0, stream>>>(z,
                                                  w1 + (size_t)l * HID * HID2,
                                                  b1 + (size_t)l * HID2,
                                                  w2 + (size_t)l * HID2 * HID,
                                                  b2 + (size_t)l * HID,
                                                  houts[l], N);
        hprev = houts[l];
    }
    final_kernel<<<grid_node, blk, 0, stream>>>(x, h1, h2, h3, lin_w, lin_b, out, N);
}